// Round 9
// baseline (203.929 us; speedup 1.0000x reference)
//
#include <hip/hip_runtime.h>
#include <stdint.h>

#define DEV __device__ __forceinline__

typedef __attribute__((ext_vector_type(4))) float f32x4;
typedef __attribute__((ext_vector_type(8))) __bf16 bf16x8;
typedef __attribute__((ext_vector_type(4))) __bf16 bf16x4;
typedef __attribute__((ext_vector_type(8))) short short8;
typedef __attribute__((ext_vector_type(4))) unsigned short u16x4;

DEV unsigned short f2bf_n(float f) {             // native cvt (RNE, 1 op)
    __bf16 h = (__bf16)f;
    return __builtin_bit_cast(unsigned short, h);
}
DEV bf16x8 ld8(const unsigned short* p) {        // 16B vector load (LDS or global)
    short8 v = *(const short8*)p;
    return __builtin_bit_cast(bf16x8, v);
}
// async global->LDS DMA, 16B per lane. lds base wave-uniform; HW adds lane*16.
DEV void ldsdma16(unsigned short* lds, const unsigned short* g) {
    __builtin_amdgcn_global_load_lds(
        (const __attribute__((address_space(1))) unsigned int*)g,
        (__attribute__((address_space(3))) unsigned int*)lds, 16, 0, 0);
}

// ---------------------------------------------------------------------------
// Pre-convert f32 -> bf16: X (4.19M el) then Wq|Wk|Wv|Wo (1.05M each).
// ---------------------------------------------------------------------------
__global__ __launch_bounds__(256) void conv_kernel(
    const float* __restrict__ X,
    const float* __restrict__ Wq, const float* __restrict__ Wk,
    const float* __restrict__ Wv, const float* __restrict__ Wo,
    unsigned short* __restrict__ Xb, unsigned short* __restrict__ Wb)
{
    int c = blockIdx.x * 256 + threadIdx.x;      // chunk of 4 floats
    const float* src;
    unsigned short* dst;
    if (c < 1048576) {
        src = X + c * 4; dst = Xb + c * 4;
    } else {
        int c2 = c - 1048576;
        int wsel = c2 >> 18;
        int off = (c2 & 262143) * 4;
        const float* ws_[4] = { Wq, Wk, Wv, Wo };
        src = ws_[wsel] + off;
        dst = Wb + wsel * 1048576 + off;
    }
    f32x4 v = *(const f32x4*)src;
    bf16x4 b = { (__bf16)v[0], (__bf16)v[1], (__bf16)v[2], (__bf16)v[3] };
    *(bf16x4*)dst = b;
}

// ---------------------------------------------------------------------------
// Fused QKV projection — BK=32 double-buffered DMA pipeline (1 barrier/kt,
// DMA for tile kt+1 issued before compute of tile kt).
// grid (32, 24): y: 0-7 Q, 8-15 K, 16-23 V.
// LDS: ping-pong staging (2 x 8192 el) unioned with repack tile (128x136 el).
// Swizzle: 32-col rows = 4 chunks of 8 el; chunk c stored at slot
// c ^ ((row>>1)&3)  -> conflict-free ds_read_b128 fragments.
// ---------------------------------------------------------------------------
__global__ __launch_bounds__(256) void qkv_kernel(
    const unsigned short* __restrict__ Xb, const unsigned short* __restrict__ Wb,
    const float* __restrict__ bq, const float* __restrict__ bk,
    const float* __restrict__ bv,
    unsigned short* __restrict__ Qws, unsigned short* __restrict__ Kws,
    unsigned short* __restrict__ VT)
{
    __shared__ __align__(16) unsigned short SMEM[17408];

    const int t = threadIdx.x;
    const int lane = t & 63, w = t >> 6;
    const int wm = w & 1, wn = w >> 1;
    const int l15 = lane & 15, grp = lane >> 4;
    const int m0 = blockIdx.x * 128;
    const int which = blockIdx.y >> 3;
    const int e0 = (blockIdx.y & 7) * 128;

    const unsigned short* Wmat = Wb + which * 1048576;
    const float* bias = (which == 0) ? bq : (which == 1) ? bk : bv;

    const int drow = lane >> 2;          // 0..15: row within 16-row DMA instr
    const int dc   = lane & 3;           // chunk slot within row

    f32x4 acc[4][4];
#pragma unroll
    for (int i = 0; i < 4; ++i)
#pragma unroll
        for (int j = 0; j < 4; ++j) acc[i][j] = (f32x4){0.f, 0.f, 0.f, 0.f};

    // prologue: stage tile 0 into buffer 0
    {
        const int k0 = 0;
#pragma unroll
        for (int ii = 0; ii < 2; ++ii) {
            int i = w * 2 + ii;                      // 0..7
            int row = i * 16 + drow;
            int cg = dc ^ ((row >> 1) & 3);
            ldsdma16(&SMEM[i * 512], &Xb[(m0 + row) * 1024 + k0 + cg * 8]);
            ldsdma16(&SMEM[4096 + i * 512], &Wmat[(e0 + row) * 1024 + k0 + cg * 8]);
        }
    }

    for (int kt = 0; kt < 32; ++kt) {
        const int p = kt & 1;
        __syncthreads();                 // drains DMA(kt) + readers of buf p^1
        if (kt + 1 < 32) {               // issue DMA(kt+1) under compute(kt)
            const int k0 = (kt + 1) * 32;
            unsigned short* dA = SMEM + (p ^ 1) * 8192;
#pragma unroll
            for (int ii = 0; ii < 2; ++ii) {
                int i = w * 2 + ii;
                int row = i * 16 + drow;
                int cg = dc ^ ((row >> 1) & 3);
                ldsdma16(&dA[i * 512], &Xb[(m0 + row) * 1024 + k0 + cg * 8]);
                ldsdma16(&dA[4096 + i * 512],
                         &Wmat[(e0 + row) * 1024 + k0 + cg * 8]);
            }
        }
        const unsigned short* As = SMEM + p * 8192;
        const unsigned short* Bs = As + 4096;
        bf16x8 af[4], bfr[4];
#pragma unroll
        for (int i = 0; i < 4; ++i) {
            int r = wm * 64 + i * 16 + l15;
            af[i] = ld8(&As[r * 32 + ((grp ^ ((r >> 1) & 3)) << 3)]);
        }
#pragma unroll
        for (int j = 0; j < 4; ++j) {
            int r = wn * 64 + j * 16 + l15;
            bfr[j] = ld8(&Bs[r * 32 + ((grp ^ ((r >> 1) & 3)) << 3)]);
        }
#pragma unroll
        for (int i = 0; i < 4; ++i)
#pragma unroll
            for (int j = 0; j < 4; ++j)
                acc[i][j] = __builtin_amdgcn_mfma_f32_16x16x32_bf16(
                    af[i], bfr[j], acc[i][j], 0, 0, 0);
    }

    __syncthreads();                     // all waves done reading staging bufs
    const int b = m0 >> 11;

    if (which == 2) {
        // ---- V: repack [e][token], then coalesced V^T stores ----
#pragma unroll
        for (int j = 0; j < 4; ++j) {
            int e = e0 + wn * 64 + j * 16 + l15;
            float bv_ = bias[e];
#pragma unroll
            for (int i = 0; i < 4; ++i) {
                u16x4 pk;
#pragma unroll
                for (int r = 0; r < 4; ++r) pk[r] = f2bf_n(acc[i][j][r] + bv_);
                *(u16x4*)&SMEM[(wn * 64 + j * 16 + l15) * 136 +
                               wm * 64 + i * 16 + grp * 4] = pk;
            }
        }
        __syncthreads();
        const int s0 = m0 & 2047;
#pragma unroll
        for (int round = 0; round < 8; ++round) {
            int dhl = (t >> 4) + round * 16;     // 0..127 over e-tile
            int chunk = t & 15;                  // 16 x 8el = 128 tokens
            int h = (e0 + dhl) >> 6, dh = (e0 + dhl) & 63;
            *(short8*)&VT[((b * 16 + h) * 64 + dh) * 2048 + s0 + chunk * 8] =
                *(const short8*)&SMEM[dhl * 136 + chunk * 8];
        }
    } else {
        // ---- Q / K: repack [token][e], then coalesced 16B stores ----
        const float scale = (which == 0) ? 0.125f : 1.0f;
#pragma unroll
        for (int j = 0; j < 4; ++j) {
            int e = e0 + wn * 64 + j * 16 + l15;
            float bv_ = bias[e];
#pragma unroll
            for (int i = 0; i < 4; ++i)
#pragma unroll
                for (int r = 0; r < 4; ++r)
                    SMEM[(wm * 64 + i * 16 + grp * 4 + r) * 136 +
                         wn * 64 + j * 16 + l15] =
                        f2bf_n((acc[i][j][r] + bv_) * scale);
        }
        __syncthreads();
        unsigned short* dst = (which == 0) ? Qws : Kws;
#pragma unroll
        for (int round = 0; round < 8; ++round) {
            int tl = (t >> 4) + round * 16;      // 0..127 token row
            int chunk = t & 15;                  // 16 x 8el = 128 e cols
            int e = e0 + chunk * 8;
            int h = e >> 6, dh = e & 63;
            int s = (m0 & 2047) + tl;
            *(short8*)&dst[((b * 16 + h) * 2048 + s) * 64 + dh] =
                *(const short8*)&SMEM[tl * 136 + chunk * 8];
        }
    }
}

// ---------------------------------------------------------------------------
// Flash attention: LDS-staged K/V shared by EIGHT waves (512-thread block).
// grid (16, 32): x = q-tile (128 rows), y = b*16+h. Each wave owns 16 q rows.
// K/V staged via async ldsdma (unpadded + xor swizzle). P wave-private.
// Row-sum l via constant ones B-frag. 2 barriers/tile. [UNCHANGED: control]
// ---------------------------------------------------------------------------
__global__ __launch_bounds__(512, 8) void attn_kernel(
    const unsigned short* __restrict__ Qws, const unsigned short* __restrict__ Kws,
    const unsigned short* __restrict__ VT, const float* __restrict__ mask,
    unsigned short* __restrict__ Xattn)
{
    __shared__ __align__(16) unsigned short Ks[64 * 64];   // [key][dh], swizzled
    __shared__ __align__(16) unsigned short Vs[64 * 64];   // [dh][key], swizzled
    __shared__ __align__(16) unsigned short Ps[128 * 72];  // 8 waves x 16 rows

    const int t = threadIdx.x;
    const int lane = t & 63, w = t >> 6;     // 8 waves
    const int l15 = lane & 15, grp = lane >> 4;
    const int q0 = blockIdx.x * 128;
    const int bh = blockIdx.y;
    const int b = bh >> 4;
    const int srow = lane >> 3, sc_ = lane & 7;

    const unsigned short* Kp = Kws + (size_t)bh * 131072;  // [key][dh]
    const unsigned short* Vp = VT  + (size_t)bh * 131072;  // [dh][key]

    bf16x8 qf[2];
#pragma unroll
    for (int c = 0; c < 2; ++c)
        qf[c] = ld8(&Qws[(bh * 2048 + q0 + w * 16 + l15) * 64 + c * 32 + grp * 8]);

    short onev = (l15 == 0) ? (short)0x3F80 : (short)0;
    short8 ov = { onev, onev, onev, onev, onev, onev, onev, onev };
    bf16x8 ones_f = __builtin_bit_cast(bf16x8, ov);

    f32x4 acc[5];   // acc[4] col 0 = l per row
#pragma unroll
    for (int d = 0; d < 5; ++d) acc[d] = (f32x4){0.f, 0.f, 0.f, 0.f};

    for (int kt = 0; kt < 32; ++kt) {
        const int k0 = kt * 64;
        __syncthreads();                 // prev tile's readers done
        {   // wave w stages 8 rows of Ks and 8 rows of Vs (1 DMA instr each)
            int row = w * 8 + srow;
            int cs = sc_ ^ (row & 7);
            ldsdma16(&Ks[w * 512], &Kp[(k0 + row) * 64 + cs * 8]);
            ldsdma16(&Vs[w * 512], &Vp[row * 2048 + k0 + cs * 8]);
        }
        float mc[4];
#pragma unroll
        for (int n = 0; n < 4; ++n) mc[n] = mask[b * 2048 + k0 + n * 16 + l15];
        __syncthreads();                 // DMA drained

#pragma unroll
        for (int n = 0; n < 4; ++n) {
            int rK = n * 16 + l15;
            bf16x8 kf0 = ld8(&Ks[rK * 64 + ((grp ^ (rK & 7)) << 3)]);
            bf16x8 kf1 = ld8(&Ks[rK * 64 + (((4 + grp) ^ (rK & 7)) << 3)]);
            f32x4 z = (f32x4){0.f, 0.f, 0.f, 0.f};
            z = __builtin_amdgcn_mfma_f32_16x16x32_bf16(qf[0], kf0, z, 0, 0, 0);
            z = __builtin_amdgcn_mfma_f32_16x16x32_bf16(qf[1], kf1, z, 0, 0, 0);
#pragma unroll
            for (int r = 0; r < 4; ++r) {
                float p = __expf(z[r]) * mc[n];
                Ps[(w * 16 + grp * 4 + r) * 72 + n * 16 + l15] = f2bf_n(p);
            }
        }
        // wave-private Ps: in-wave lgkmcnt ordering suffices, no barrier

        bf16x8 pf[2];
#pragma unroll
        for (int c = 0; c < 2; ++c)
            pf[c] = ld8(&Ps[(w * 16 + l15) * 72 + c * 32 + grp * 8]);

#pragma unroll
        for (int d = 0; d < 4; ++d) {
            int rV = d * 16 + l15;
            bf16x8 vf0 = ld8(&Vs[rV * 64 + ((grp ^ (rV & 7)) << 3)]);
            bf16x8 vf1 = ld8(&Vs[rV * 64 + (((4 + grp) ^ (rV & 7)) << 3)]);
            acc[d] = __builtin_amdgcn_mfma_f32_16x16x32_bf16(pf[0], vf0, acc[d], 0, 0, 0);
            acc[d] = __builtin_amdgcn_mfma_f32_16x16x32_bf16(pf[1], vf1, acc[d], 0, 0, 0);
        }
        acc[4] = __builtin_amdgcn_mfma_f32_16x16x32_bf16(pf[0], ones_f, acc[4], 0, 0, 0);
        acc[4] = __builtin_amdgcn_mfma_f32_16x16x32_bf16(pf[1], ones_f, acc[4], 0, 0, 0);
    }

#pragma unroll
    for (int r = 0; r < 4; ++r) {
        int q = q0 + w * 16 + grp * 4 + r;
        float mq = mask[b * 2048 + q];
        float lr = __shfl(acc[4][r], lane & 48, 64);
        float inv = mq / (lr + 1e-13f);
#pragma unroll
        for (int d = 0; d < 4; ++d)
            Xattn[(b * 2048 + q) * 1024 + (bh & 15) * 64 + d * 16 + l15] =
                f2bf_n(acc[d][r] * inv);
    }
}

// ---------------------------------------------------------------------------
// Output projection — BK=32 double-buffered DMA pipeline, 64x128 tiles,
// grid (64, 8) = 512 blocks. f32 out.
// ---------------------------------------------------------------------------
__global__ __launch_bounds__(256) void oproj_kernel(
    const unsigned short* __restrict__ A, const unsigned short* __restrict__ W,
    const float* __restrict__ bias, float* __restrict__ out)
{
    // per buffer: As 64x32 (2048 el) + Bs 128x32 (4096 el) = 6144 el
    __shared__ __align__(16) unsigned short SMEM[12288];

    const int t = threadIdx.x;
    const int lane = t & 63, w = t >> 6;
    const int l15 = lane & 15, grp = lane >> 4;
    const int m0 = blockIdx.x * 64;
    const int e0 = blockIdx.y * 128;
    const int drow = lane >> 2, dc = lane & 3;

    f32x4 acc[4][2];
#pragma unroll
    for (int i = 0; i < 4; ++i)
#pragma unroll
        for (int j = 0; j < 2; ++j) acc[i][j] = (f32x4){0.f, 0.f, 0.f, 0.f};

    {   // prologue: tile 0 -> buffer 0
        const int k0 = 0;
        {   // A: 4 instrs, 1 per wave
            int row = w * 16 + drow;
            int cg = dc ^ ((row >> 1) & 3);
            ldsdma16(&SMEM[w * 512], &A[(m0 + row) * 1024 + k0 + cg * 8]);
        }
#pragma unroll
        for (int ii = 0; ii < 2; ++ii) {     // B: 8 instrs, 2 per wave
            int i = w * 2 + ii;
            int row = i * 16 + drow;
            int cg = dc ^ ((row >> 1) & 3);
            ldsdma16(&SMEM[2048 + i * 512], &W[(e0 + row) * 1024 + k0 + cg * 8]);
        }
    }

    for (int kt = 0; kt < 32; ++kt) {
        const int p = kt & 1;
        __syncthreads();
        if (kt + 1 < 32) {
            const int k0 = (kt + 1) * 32;
            unsigned short* dB = SMEM + (p ^ 1) * 6144;
            {
                int row = w * 16 + drow;
                int cg = dc ^ ((row >> 1) & 3);
                ldsdma16(&dB[w * 512], &A[(m0 + row) * 1024 + k0 + cg * 8]);
            }
#pragma unroll
            for (int ii = 0; ii < 2; ++ii) {
                int i = w * 2 + ii;
                int row = i * 16 + drow;
                int cg = dc ^ ((row >> 1) & 3);
                ldsdma16(&dB[2048 + i * 512], &W[(e0 + row) * 1024 + k0 + cg * 8]);
            }
        }
        const unsigned short* As = SMEM + p * 6144;
        const unsigned short* Bs = As + 2048;
        bf16x8 af[4], bfr[2];
#pragma unroll
        for (int i = 0; i < 4; ++i) {
            int r = i * 16 + l15;
            af[i] = ld8(&As[r * 32 + ((grp ^ ((r >> 1) & 3)) << 3)]);
        }
#pragma unroll
        for (int j = 0; j < 2; ++j) {
            int r = w * 32 + j * 16 + l15;
            bfr[j] = ld8(&Bs[r * 32 + ((grp ^ ((r >> 1) & 3)) << 3)]);
        }
#pragma unroll
        for (int i = 0; i < 4; ++i)
#pragma unroll
            for (int j = 0; j < 2; ++j)
                acc[i][j] = __builtin_amdgcn_mfma_f32_16x16x32_bf16(
                    af[i], bfr[j], acc[i][j], 0, 0, 0);
    }

#pragma unroll
    for (int j = 0; j < 2; ++j) {
        int e = e0 + w * 32 + j * 16 + l15;
        float bv_ = bias[e];
#pragma unroll
        for (int i = 0; i < 4; ++i)
#pragma unroll
            for (int r = 0; r < 4; ++r) {
                int token = m0 + i * 16 + grp * 4 + r;
                out[token * 1024 + e] = acc[i][j][r] + bv_;
            }
    }
}

extern "C" void kernel_launch(void* const* d_in, const int* in_sizes, int n_in,
                              void* d_out, int out_size, void* d_ws, size_t ws_size,
                              hipStream_t stream) {
    const float* x    = (const float*)d_in[0];
    const float* mask = (const float*)d_in[1];
    const float* Wq   = (const float*)d_in[2];
    const float* bq   = (const float*)d_in[3];
    const float* Wk   = (const float*)d_in[4];
    const float* bk   = (const float*)d_in[5];
    const float* Wv   = (const float*)d_in[6];
    const float* bv   = (const float*)d_in[7];
    const float* Wo   = (const float*)d_in[8];
    const float* bo   = (const float*)d_in[9];
    float* out = (float*)d_out;

    unsigned short* Qws   = (unsigned short*)d_ws;   // u16 element offsets:
    unsigned short* Kws   = Qws + 4194304;
    unsigned short* VT    = Qws + 8388608;
    unsigned short* Xattn = Qws + 12582912;
    unsigned short* Xb    = Qws + 16777216;
    unsigned short* Wb    = Qws + 20971520;          // [Wq|Wk|Wv|Wo], end = 48 MB

    conv_kernel<<<dim3(8192), 256, 0, stream>>>(x, Wq, Wk, Wv, Wo, Xb, Wb);
    qkv_kernel<<<dim3(32, 24), 256, 0, stream>>>(Xb, Wb, bq, bk, bv, Qws, Kws, VT);
    attn_kernel<<<dim3(16, 32), 512, 0, stream>>>(Qws, Kws, VT, mask, Xattn);
    oproj_kernel<<<dim3(64, 8), 256, 0, stream>>>(Xattn, Wb + 3145728, bo, out);
}

// Round 10
// 202.097 us; speedup vs baseline: 1.0091x; 1.0091x over previous
//
#include <hip/hip_runtime.h>
#include <stdint.h>

#define DEV __device__ __forceinline__

typedef __attribute__((ext_vector_type(4))) float f32x4;
typedef __attribute__((ext_vector_type(16))) float f32x16;
typedef __attribute__((ext_vector_type(8))) __bf16 bf16x8;
typedef __attribute__((ext_vector_type(4))) __bf16 bf16x4;
typedef __attribute__((ext_vector_type(8))) short short8;
typedef __attribute__((ext_vector_type(4))) unsigned short u16x4;

DEV unsigned short f2bf_n(float f) {             // native cvt (RNE, 1 op)
    __bf16 h = (__bf16)f;
    return __builtin_bit_cast(unsigned short, h);
}
DEV bf16x8 ld8(const unsigned short* p) {        // 16B vector load (LDS or global)
    short8 v = *(const short8*)p;
    return __builtin_bit_cast(bf16x8, v);
}
// async global->LDS DMA, 16B per lane. lds base wave-uniform; HW adds lane*16.
DEV void ldsdma16(unsigned short* lds, const unsigned short* g) {
    __builtin_amdgcn_global_load_lds(
        (const __attribute__((address_space(1))) unsigned int*)g,
        (__attribute__((address_space(3))) unsigned int*)lds, 16, 0, 0);
}

// ---------------------------------------------------------------------------
// Pre-convert f32 -> bf16: X (4.19M el) then Wq|Wk|Wv|Wo (1.05M each).
// ---------------------------------------------------------------------------
__global__ __launch_bounds__(256) void conv_kernel(
    const float* __restrict__ X,
    const float* __restrict__ Wq, const float* __restrict__ Wk,
    const float* __restrict__ Wv, const float* __restrict__ Wo,
    unsigned short* __restrict__ Xb, unsigned short* __restrict__ Wb)
{
    int c = blockIdx.x * 256 + threadIdx.x;      // chunk of 4 floats
    const float* src;
    unsigned short* dst;
    if (c < 1048576) {
        src = X + c * 4; dst = Xb + c * 4;
    } else {
        int c2 = c - 1048576;
        int wsel = c2 >> 18;
        int off = (c2 & 262143) * 4;
        const float* ws_[4] = { Wq, Wk, Wv, Wo };
        src = ws_[wsel] + off;
        dst = Wb + wsel * 1048576 + off;
    }
    f32x4 v = *(const f32x4*)src;
    bf16x4 b = { (__bf16)v[0], (__bf16)v[1], (__bf16)v[2], (__bf16)v[3] };
    *(bf16x4*)dst = b;
}

// ---------------------------------------------------------------------------
// Fused QKV projection — round-8 structure (BK=64, single-buffer DMA staging;
// dbuf regressed in round 9: fewer MFMAs per barrier). grid (32, 24).
// ALL epilogues repack through LDS -> fully coalesced 16B stores.
// ---------------------------------------------------------------------------
__global__ __launch_bounds__(256) void qkv_kernel(
    const unsigned short* __restrict__ Xb, const unsigned short* __restrict__ Wb,
    const float* __restrict__ bq, const float* __restrict__ bk,
    const float* __restrict__ bv,
    unsigned short* __restrict__ Qws, unsigned short* __restrict__ Kws,
    unsigned short* __restrict__ VT)
{
    // union: staging As|Bs (2 x 8192 el) vs repack tile (128 x 136 el)
    __shared__ __align__(16) unsigned short SMEM[17408];
    unsigned short* As = SMEM;
    unsigned short* Bs = SMEM + 8192;

    const int t = threadIdx.x;
    const int lane = t & 63, w = t >> 6;
    const int wm = w & 1, wn = w >> 1;
    const int l15 = lane & 15, grp = lane >> 4;
    const int m0 = blockIdx.x * 128;
    const int which = blockIdx.y >> 3;
    const int e0 = (blockIdx.y & 7) * 128;

    const unsigned short* Wmat = Wb + which * 1048576;
    const float* bias = (which == 0) ? bq : (which == 1) ? bk : bv;

    const int srow = lane >> 3;          // row within 8-row DMA chunk
    const int sc_  = lane & 7;           // slot within row

    f32x4 acc[4][4];
#pragma unroll
    for (int i = 0; i < 4; ++i)
#pragma unroll
        for (int j = 0; j < 4; ++j) acc[i][j] = (f32x4){0.f, 0.f, 0.f, 0.f};

    for (int kt = 0; kt < 16; ++kt) {
        const int k0 = kt * 64;
        __syncthreads();
#pragma unroll
        for (int j = 0; j < 4; ++j) {
            int row = (w * 4 + j) * 8 + srow;                // 0..127
            int cs = sc_ ^ (row & 7);                        // global-side swizzle
            ldsdma16(&As[(w * 4 + j) * 512],
                     &Xb[(m0 + row) * 1024 + k0 + cs * 8]);
            ldsdma16(&Bs[(w * 4 + j) * 512],
                     &Wmat[(e0 + row) * 1024 + k0 + cs * 8]);
        }
        __syncthreads();
#pragma unroll
        for (int kk = 0; kk < 64; kk += 32) {
            const int cb = kk >> 3;
            bf16x8 af[4], bfr[4];
#pragma unroll
            for (int i = 0; i < 4; ++i) {
                int r = wm * 64 + i * 16 + l15;
                af[i] = ld8(&As[r * 64 + (((cb + grp) ^ (r & 7)) << 3)]);
            }
#pragma unroll
            for (int j = 0; j < 4; ++j) {
                int r = wn * 64 + j * 16 + l15;
                bfr[j] = ld8(&Bs[r * 64 + (((cb + grp) ^ (r & 7)) << 3)]);
            }
#pragma unroll
            for (int i = 0; i < 4; ++i)
#pragma unroll
                for (int j = 0; j < 4; ++j)
                    acc[i][j] = __builtin_amdgcn_mfma_f32_16x16x32_bf16(
                        af[i], bfr[j], acc[i][j], 0, 0, 0);
        }
    }

    __syncthreads();                     // all waves done reading As/Bs
    const int b = m0 >> 11;

    if (which == 2) {
        // ---- V: repack [e][token], then coalesced V^T stores ----
#pragma unroll
        for (int j = 0; j < 4; ++j) {
            int e = e0 + wn * 64 + j * 16 + l15;
            float bv_ = bias[e];
#pragma unroll
            for (int i = 0; i < 4; ++i) {
                u16x4 pk;
#pragma unroll
                for (int r = 0; r < 4; ++r) pk[r] = f2bf_n(acc[i][j][r] + bv_);
                *(u16x4*)&SMEM[(wn * 64 + j * 16 + l15) * 136 +
                               wm * 64 + i * 16 + grp * 4] = pk;
            }
        }
        __syncthreads();
        const int s0 = m0 & 2047;
#pragma unroll
        for (int round = 0; round < 8; ++round) {
            int dhl = (t >> 4) + round * 16;     // 0..127 over e-tile
            int chunk = t & 15;                  // 16 x 8el = 128 tokens
            int h = (e0 + dhl) >> 6, dh = (e0 + dhl) & 63;
            *(short8*)&VT[((b * 16 + h) * 64 + dh) * 2048 + s0 + chunk * 8] =
                *(const short8*)&SMEM[dhl * 136 + chunk * 8];
        }
    } else {
        // ---- Q / K: repack [token][e], then coalesced 16B stores ----
        const float scale = (which == 0) ? 0.125f : 1.0f;
#pragma unroll
        for (int j = 0; j < 4; ++j) {
            int e = e0 + wn * 64 + j * 16 + l15;
            float bv_ = bias[e];
#pragma unroll
            for (int i = 0; i < 4; ++i)
#pragma unroll
                for (int r = 0; r < 4; ++r)
                    SMEM[(wm * 64 + i * 16 + grp * 4 + r) * 136 +
                         wn * 64 + j * 16 + l15] =
                        f2bf_n((acc[i][j][r] + bv_) * scale);
        }
        __syncthreads();
        unsigned short* dst = (which == 0) ? Qws : Kws;
#pragma unroll
        for (int round = 0; round < 8; ++round) {
            int tl = (t >> 4) + round * 16;      // 0..127 token row
            int chunk = t & 15;                  // 16 x 8el = 128 e cols
            int e = e0 + chunk * 8;
            int h = e >> 6, dh = e & 63;
            int s = (m0 & 2047) + tl;
            *(short8*)&dst[((b * 16 + h) * 2048 + s) * 64 + dh] =
                *(const short8*)&SMEM[tl * 136 + chunk * 8];
        }
    }
}

// ---------------------------------------------------------------------------
// Flash attention v3: 32x32x16 MFMAs (2x FLOP per LDS fragment byte).
// grid (16, 32): x = q-tile (128 rows), y = b*16+h. 4 waves x 32 q rows.
// Layouts (gfx950, guide-verified): A/B: m|n=lane&31, k=(lane>>5)*8+j;
// C/D: col=lane&31, row=(reg&3)+8*(reg>>2)+4*(lane>>5).
// K/V staged via ldsdma (xor swizzle); P wave-private via LDS (pad 72);
// row-sum l via ones B-frag (n==0). 2 barriers/tile.
// ---------------------------------------------------------------------------
__global__ __launch_bounds__(256) void attn_kernel(
    const unsigned short* __restrict__ Qws, const unsigned short* __restrict__ Kws,
    const unsigned short* __restrict__ VT, const float* __restrict__ mask,
    unsigned short* __restrict__ Xattn)
{
    __shared__ __align__(16) unsigned short Ks[64 * 64];   // [key][dh], swizzled
    __shared__ __align__(16) unsigned short Vs[64 * 64];   // [dh][key], swizzled
    __shared__ __align__(16) unsigned short Ps[128 * 72];  // 4 waves x 32 rows

    const int t = threadIdx.x;
    const int lane = t & 63, w = t >> 6;     // 4 waves
    const int l31 = lane & 31, half = lane >> 5;
    const int q0 = blockIdx.x * 128;
    const int bh = blockIdx.y;
    const int b = bh >> 4;
    const int srow = lane >> 3, sc_ = lane & 7;

    const unsigned short* Kp = Kws + (size_t)bh * 131072;  // [key][dh]
    const unsigned short* Vp = VT  + (size_t)bh * 131072;  // [dh][key]

    // Q A-frags (persistent): qf[s] = Q[q0+w*32+l31][s*16 + half*8 .. +7]
    bf16x8 qf[4];
#pragma unroll
    for (int s = 0; s < 4; ++s)
        qf[s] = ld8(&Qws[(bh * 2048 + q0 + w * 32 + l31) * 64 + s * 16 + half * 8]);

    // ones B-frag: B[n][k]=1 iff n==0  (lanes 0 and 32 hold ones)
    short onev = (l31 == 0) ? (short)0x3F80 : (short)0;
    short8 ov = { onev, onev, onev, onev, onev, onev, onev, onev };
    bf16x8 ones_f = __builtin_bit_cast(bf16x8, ov);

    f32x16 accd[2], accl;
#pragma unroll
    for (int d = 0; d < 2; ++d)
#pragma unroll
        for (int r = 0; r < 16; ++r) accd[d][r] = 0.f;
#pragma unroll
    for (int r = 0; r < 16; ++r) accl[r] = 0.f;

    for (int kt = 0; kt < 32; ++kt) {
        const int k0 = kt * 64;
        __syncthreads();                 // prev tile's readers done
#pragma unroll
        for (int ii = 0; ii < 2; ++ii) { // wave stages 16 rows of Ks and Vs
            int row = w * 16 + ii * 8 + srow;
            int cs = sc_ ^ (row & 7);
            ldsdma16(&Ks[(w * 2 + ii) * 512], &Kp[(k0 + row) * 64 + cs * 8]);
            ldsdma16(&Vs[(w * 2 + ii) * 512], &Vp[row * 2048 + k0 + cs * 8]);
        }
        float mc[2];
        mc[0] = mask[b * 2048 + k0 + l31];
        mc[1] = mask[b * 2048 + k0 + 32 + l31];
        __syncthreads();                 // DMA drained

        // S = Q.K^T per 32-key group -> P = exp(s)*m into wave-private Ps
#pragma unroll
        for (int g = 0; g < 2; ++g) {
            f32x16 z;
#pragma unroll
            for (int r = 0; r < 16; ++r) z[r] = 0.f;
            int rK = g * 32 + l31;       // key row in Ks
#pragma unroll
            for (int s = 0; s < 4; ++s) {
                int chunk = s * 2 + half;
                bf16x8 kf = ld8(&Ks[rK * 64 + ((chunk ^ (rK & 7)) << 3)]);
                z = __builtin_amdgcn_mfma_f32_32x32x16_bf16(qf[s], kf, z, 0, 0, 0);
            }
#pragma unroll
            for (int r = 0; r < 16; ++r) {
                float p = __expf(z[r]) * mc[g];
                int ql = (r & 3) + 8 * (r >> 2) + 4 * half;  // 0..31
                Ps[(w * 32 + ql) * 72 + g * 32 + l31] = f2bf_n(p);
            }
        }
        // wave-private Ps: in-wave lgkmcnt ordering suffices, no barrier

        bf16x8 pf[4];
#pragma unroll
        for (int s = 0; s < 4; ++s)
            pf[s] = ld8(&Ps[(w * 32 + l31) * 72 + s * 16 + half * 8]);

#pragma unroll
        for (int d = 0; d < 2; ++d) {
            int rV = d * 32 + l31;       // dh row in Vs
#pragma unroll
            for (int s = 0; s < 4; ++s) {
                int chunk = s * 2 + half;
                bf16x8 vf = ld8(&Vs[rV * 64 + ((chunk ^ (rV & 7)) << 3)]);
                accd[d] = __builtin_amdgcn_mfma_f32_32x32x16_bf16(
                    pf[s], vf, accd[d], 0, 0, 0);
            }
        }
#pragma unroll
        for (int s = 0; s < 4; ++s)
            accl = __builtin_amdgcn_mfma_f32_32x32x16_bf16(pf[s], ones_f, accl, 0, 0, 0);
    }

    // epilogue: l[q] sits in col 0 (lane half*32), reg r
#pragma unroll
    for (int r = 0; r < 16; ++r) {
        int ql = (r & 3) + 8 * (r >> 2) + 4 * half;
        int q = q0 + w * 32 + ql;
        float mq = mask[b * 2048 + q];
        float lr = __shfl(accl[r], half * 32, 64);
        float inv = mq / (lr + 1e-13f);
#pragma unroll
        for (int d = 0; d < 2; ++d)
            Xattn[(b * 2048 + q) * 1024 + (bh & 15) * 64 + d * 32 + l31] =
                f2bf_n(accd[d][r] * inv);
    }
}

// ---------------------------------------------------------------------------
// Output projection — round-8 structure (BK=64 single-buffer), 64x128 tiles,
// grid (64, 8) = 512 blocks. f32 out.
// ---------------------------------------------------------------------------
__global__ __launch_bounds__(256) void oproj_kernel(
    const unsigned short* __restrict__ A, const unsigned short* __restrict__ W,
    const float* __restrict__ bias, float* __restrict__ out)
{
    __shared__ __align__(16) unsigned short As[64 * 64];
    __shared__ __align__(16) unsigned short Bs[128 * 64];

    const int t = threadIdx.x;
    const int lane = t & 63, w = t >> 6;
    const int l15 = lane & 15, grp = lane >> 4;
    const int m0 = blockIdx.x * 64;
    const int e0 = blockIdx.y * 128;
    const int srow = lane >> 3, sc_ = lane & 7;

    f32x4 acc[4][2];
#pragma unroll
    for (int i = 0; i < 4; ++i)
#pragma unroll
        for (int j = 0; j < 2; ++j) acc[i][j] = (f32x4){0.f, 0.f, 0.f, 0.f};

    for (int kt = 0; kt < 16; ++kt) {
        const int k0 = kt * 64;
        __syncthreads();
#pragma unroll
        for (int jj = 0; jj < 2; ++jj) {         // A: 8 chunks, 2 per wave
            int chunk = w * 2 + jj;
            int row = chunk * 8 + srow;
            int cs = sc_ ^ (row & 7);
            ldsdma16(&As[chunk * 512], &A[(m0 + row) * 1024 + k0 + cs * 8]);
        }
#pragma unroll
        for (int jj = 0; jj < 4; ++jj) {         // B: 16 chunks, 4 per wave
            int chunk = w * 4 + jj;
            int row = chunk * 8 + srow;
            int cs = sc_ ^ (row & 7);
            ldsdma16(&Bs[chunk * 512], &W[(e0 + row) * 1024 + k0 + cs * 8]);
        }
        __syncthreads();
#pragma unroll
        for (int kk = 0; kk < 64; kk += 32) {
            const int cb = kk >> 3;
            bf16x8 af[4], bfr[2];
#pragma unroll
            for (int i = 0; i < 4; ++i) {
                int r = i * 16 + l15;
                af[i] = ld8(&As[r * 64 + (((cb + grp) ^ (r & 7)) << 3)]);
            }
#pragma unroll
            for (int j = 0; j < 2; ++j) {
                int r = w * 32 + j * 16 + l15;
                bfr[j] = ld8(&Bs[r * 64 + (((cb + grp) ^ (r & 7)) << 3)]);
            }
#pragma unroll
            for (int i = 0; i < 4; ++i)
#pragma unroll
                for (int j = 0; j < 2; ++j)
                    acc[i][j] = __builtin_amdgcn_mfma_f32_16x16x32_bf16(
                        af[i], bfr[j], acc[i][j], 0, 0, 0);
        }
    }

#pragma unroll
    for (int j = 0; j < 2; ++j) {
        int e = e0 + w * 32 + j * 16 + l15;
        float bv_ = bias[e];
#pragma unroll
        for (int i = 0; i < 4; ++i)
#pragma unroll
            for (int r = 0; r < 4; ++r) {
                int token = m0 + i * 16 + grp * 4 + r;
                out[token * 1024 + e] = acc[i][j][r] + bv_;
            }
    }
}

extern "C" void kernel_launch(void* const* d_in, const int* in_sizes, int n_in,
                              void* d_out, int out_size, void* d_ws, size_t ws_size,
                              hipStream_t stream) {
    const float* x    = (const float*)d_in[0];
    const float* mask = (const float*)d_in[1];
    const float* Wq   = (const float*)d_in[2];
    const float* bq   = (const float*)d_in[3];
    const float* Wk   = (const float*)d_in[4];
    const float* bk   = (const float*)d_in[5];
    const float* Wv   = (const float*)d_in[6];
    const float* bv   = (const float*)d_in[7];
    const float* Wo   = (const float*)d_in[8];
    const float* bo   = (const float*)d_in[9];
    float* out = (float*)d_out;

    unsigned short* Qws   = (unsigned short*)d_ws;   // u16 element offsets:
    unsigned short* Kws   = Qws + 4194304;
    unsigned short* VT    = Qws + 8388608;
    unsigned short* Xattn = Qws + 12582912;
    unsigned short* Xb    = Qws + 16777216;
    unsigned short* Wb    = Qws + 20971520;          // [Wq|Wk|Wv|Wo], end = 48 MB

    conv_kernel<<<dim3(8192), 256, 0, stream>>>(x, Wq, Wk, Wv, Wo, Xb, Wb);
    qkv_kernel<<<dim3(32, 24), 256, 0, stream>>>(Xb, Wb, bq, bk, bv, Qws, Kws, VT);
    attn_kernel<<<dim3(16, 32), 256, 0, stream>>>(Qws, Kws, VT, mask, Xattn);
    oproj_kernel<<<dim3(64, 8), 256, 0, stream>>>(Xattn, Wb + 3145728, bo, out);
}

// Round 11
// 189.438 us; speedup vs baseline: 1.0765x; 1.0668x over previous
//
#include <hip/hip_runtime.h>
#include <stdint.h>

#define DEV __device__ __forceinline__

typedef __attribute__((ext_vector_type(4))) float f32x4;
typedef __attribute__((ext_vector_type(16))) float f32x16;
typedef __attribute__((ext_vector_type(8))) __bf16 bf16x8;
typedef __attribute__((ext_vector_type(4))) __bf16 bf16x4;
typedef __attribute__((ext_vector_type(8))) short short8;
typedef __attribute__((ext_vector_type(4))) unsigned short u16x4;

DEV unsigned short f2bf_n(float f) {             // native cvt (RNE, 1 op)
    __bf16 h = (__bf16)f;
    return __builtin_bit_cast(unsigned short, h);
}
DEV bf16x8 ld8(const unsigned short* p) {        // 16B vector load (LDS or global)
    short8 v = *(const short8*)p;
    return __builtin_bit_cast(bf16x8, v);
}
// async global->LDS DMA, 16B per lane. lds base wave-uniform; HW adds lane*16.
DEV void ldsdma16(unsigned short* lds, const unsigned short* g) {
    __builtin_amdgcn_global_load_lds(
        (const __attribute__((address_space(1))) unsigned int*)g,
        (__attribute__((address_space(3))) unsigned int*)lds, 16, 0, 0);
}

// ---------------------------------------------------------------------------
// Pre-convert f32 -> bf16: X (4.19M el) then Wq|Wk|Wv|Wo (1.05M each).
// ---------------------------------------------------------------------------
__global__ __launch_bounds__(256) void conv_kernel(
    const float* __restrict__ X,
    const float* __restrict__ Wq, const float* __restrict__ Wk,
    const float* __restrict__ Wv, const float* __restrict__ Wo,
    unsigned short* __restrict__ Xb, unsigned short* __restrict__ Wb)
{
    int c = blockIdx.x * 256 + threadIdx.x;      // chunk of 4 floats
    const float* src;
    unsigned short* dst;
    if (c < 1048576) {
        src = X + c * 4; dst = Xb + c * 4;
    } else {
        int c2 = c - 1048576;
        int wsel = c2 >> 18;
        int off = (c2 & 262143) * 4;
        const float* ws_[4] = { Wq, Wk, Wv, Wo };
        src = ws_[wsel] + off;
        dst = Wb + wsel * 1048576 + off;
    }
    f32x4 v = *(const f32x4*)src;
    bf16x4 b = { (__bf16)v[0], (__bf16)v[1], (__bf16)v[2], (__bf16)v[3] };
    *(bf16x4*)dst = b;
}

// ---------------------------------------------------------------------------
// Fused QKV projection — round-8 structure (BK=64 single-buffer DMA staging).
// grid (32, 24). All epilogues repack via LDS -> coalesced 16B stores.
// ---------------------------------------------------------------------------
__global__ __launch_bounds__(256) void qkv_kernel(
    const unsigned short* __restrict__ Xb, const unsigned short* __restrict__ Wb,
    const float* __restrict__ bq, const float* __restrict__ bk,
    const float* __restrict__ bv,
    unsigned short* __restrict__ Qws, unsigned short* __restrict__ Kws,
    unsigned short* __restrict__ VT)
{
    __shared__ __align__(16) unsigned short SMEM[17408];
    unsigned short* As = SMEM;
    unsigned short* Bs = SMEM + 8192;

    const int t = threadIdx.x;
    const int lane = t & 63, w = t >> 6;
    const int wm = w & 1, wn = w >> 1;
    const int l15 = lane & 15, grp = lane >> 4;
    const int m0 = blockIdx.x * 128;
    const int which = blockIdx.y >> 3;
    const int e0 = (blockIdx.y & 7) * 128;

    const unsigned short* Wmat = Wb + which * 1048576;
    const float* bias = (which == 0) ? bq : (which == 1) ? bk : bv;

    const int srow = lane >> 3;
    const int sc_  = lane & 7;

    f32x4 acc[4][4];
#pragma unroll
    for (int i = 0; i < 4; ++i)
#pragma unroll
        for (int j = 0; j < 4; ++j) acc[i][j] = (f32x4){0.f, 0.f, 0.f, 0.f};

    for (int kt = 0; kt < 16; ++kt) {
        const int k0 = kt * 64;
        __syncthreads();
#pragma unroll
        for (int j = 0; j < 4; ++j) {
            int row = (w * 4 + j) * 8 + srow;
            int cs = sc_ ^ (row & 7);
            ldsdma16(&As[(w * 4 + j) * 512],
                     &Xb[(m0 + row) * 1024 + k0 + cs * 8]);
            ldsdma16(&Bs[(w * 4 + j) * 512],
                     &Wmat[(e0 + row) * 1024 + k0 + cs * 8]);
        }
        __syncthreads();
#pragma unroll
        for (int kk = 0; kk < 64; kk += 32) {
            const int cb = kk >> 3;
            bf16x8 af[4], bfr[4];
#pragma unroll
            for (int i = 0; i < 4; ++i) {
                int r = wm * 64 + i * 16 + l15;
                af[i] = ld8(&As[r * 64 + (((cb + grp) ^ (r & 7)) << 3)]);
            }
#pragma unroll
            for (int j = 0; j < 4; ++j) {
                int r = wn * 64 + j * 16 + l15;
                bfr[j] = ld8(&Bs[r * 64 + (((cb + grp) ^ (r & 7)) << 3)]);
            }
#pragma unroll
            for (int i = 0; i < 4; ++i)
#pragma unroll
                for (int j = 0; j < 4; ++j)
                    acc[i][j] = __builtin_amdgcn_mfma_f32_16x16x32_bf16(
                        af[i], bfr[j], acc[i][j], 0, 0, 0);
        }
    }

    __syncthreads();
    const int b = m0 >> 11;

    if (which == 2) {
#pragma unroll
        for (int j = 0; j < 4; ++j) {
            int e = e0 + wn * 64 + j * 16 + l15;
            float bv_ = bias[e];
#pragma unroll
            for (int i = 0; i < 4; ++i) {
                u16x4 pk;
#pragma unroll
                for (int r = 0; r < 4; ++r) pk[r] = f2bf_n(acc[i][j][r] + bv_);
                *(u16x4*)&SMEM[(wn * 64 + j * 16 + l15) * 136 +
                               wm * 64 + i * 16 + grp * 4] = pk;
            }
        }
        __syncthreads();
        const int s0 = m0 & 2047;
#pragma unroll
        for (int round = 0; round < 8; ++round) {
            int dhl = (t >> 4) + round * 16;
            int chunk = t & 15;
            int h = (e0 + dhl) >> 6, dh = (e0 + dhl) & 63;
            *(short8*)&VT[((b * 16 + h) * 64 + dh) * 2048 + s0 + chunk * 8] =
                *(const short8*)&SMEM[dhl * 136 + chunk * 8];
        }
    } else {
        const float scale = (which == 0) ? 0.125f : 1.0f;
#pragma unroll
        for (int j = 0; j < 4; ++j) {
            int e = e0 + wn * 64 + j * 16 + l15;
            float bv_ = bias[e];
#pragma unroll
            for (int i = 0; i < 4; ++i)
#pragma unroll
                for (int r = 0; r < 4; ++r)
                    SMEM[(wm * 64 + i * 16 + grp * 4 + r) * 136 +
                         wn * 64 + j * 16 + l15] =
                        f2bf_n((acc[i][j][r] + bv_) * scale);
        }
        __syncthreads();
        unsigned short* dst = (which == 0) ? Qws : Kws;
#pragma unroll
        for (int round = 0; round < 8; ++round) {
            int tl = (t >> 4) + round * 16;
            int chunk = t & 15;
            int e = e0 + chunk * 8;
            int h = e >> 6, dh = e & 63;
            int s = (m0 & 2047) + tl;
            *(short8*)&dst[((b * 16 + h) * 2048 + s) * 64 + dh] =
                *(const short8*)&SMEM[tl * 136 + chunk * 8];
        }
    }
}

// ---------------------------------------------------------------------------
// Flash attention v4: 32x32x16 MFMAs + split-K over keys.
// grid (16, 32), 512 threads (8 waves). Wave = (khalf = w>>2, qgroup = w&3).
// Block covers 128 q-rows; iteration stages 128 keys (Ks 128x64, Vs 64x128);
// wave khalf handles keys [khalf*64, khalf*64+64) for its 32 q-rows.
// Partials are linear (no-max softmax): O = O0+O1, l = l0+l1 -> LDS merge.
// Layouts (verified, absmax-exact round 10): A/B m|n=lane&31, k=(lane>>5)*8+j;
// C/D col=lane&31, row=(reg&3)+8*(reg>>2)+4*(lane>>5).
// ---------------------------------------------------------------------------
__global__ __launch_bounds__(512, 4) void attn_kernel(
    const unsigned short* __restrict__ Qws, const unsigned short* __restrict__ Kws,
    const unsigned short* __restrict__ VT, const float* __restrict__ mask,
    unsigned short* __restrict__ Xattn)
{
    // Ks 128x64 (8192 el) | Vs 64x128 (8192 el) | Ps 8x32x72 (18432 el)
    __shared__ __align__(16) unsigned short SMEM[34816];
    unsigned short* Ks = SMEM;                    // [key][dh],  8-chunk swizzle
    unsigned short* Vs = SMEM + 8192;             // [dh][key], 16-chunk swizzle
    unsigned short* Ps = SMEM + 16384;            // wave-private 32-row strips
    float* mrg = (float*)SMEM;                    // merge overlay (48 KB fits)

    const int t = threadIdx.x;
    const int lane = t & 63, w = t >> 6;          // 8 waves
    const int l31 = lane & 31, half = lane >> 5;
    const int qg = w & 3, khalf = w >> 2;
    const int q0 = blockIdx.x * 128;
    const int bh = blockIdx.y;
    const int b = bh >> 4;

    const unsigned short* Kp = Kws + (size_t)bh * 131072;  // [key][dh]
    const unsigned short* Vp = VT  + (size_t)bh * 131072;  // [dh][key]

    // Q A-frags (persistent)
    bf16x8 qf[4];
#pragma unroll
    for (int s = 0; s < 4; ++s)
        qf[s] = ld8(&Qws[(bh * 2048 + q0 + qg * 32 + l31) * 64 + s * 16 + half * 8]);

    // ones B-frag: B[n][k]=1 iff n==0
    short onev = (l31 == 0) ? (short)0x3F80 : (short)0;
    short8 ov = { onev, onev, onev, onev, onev, onev, onev, onev };
    bf16x8 ones_f = __builtin_bit_cast(bf16x8, ov);

    f32x16 accd[2], accl;
#pragma unroll
    for (int d = 0; d < 2; ++d)
#pragma unroll
        for (int r = 0; r < 16; ++r) accd[d][r] = 0.f;
#pragma unroll
    for (int r = 0; r < 16; ++r) accl[r] = 0.f;

    for (int kb = 0; kb < 16; ++kb) {
        const int k0 = kb * 128;
        __syncthreads();                 // prev tile's readers done
        // --- stage Ks: 16 DMA instrs (8 rows of 128B each), 2 per wave ---
#pragma unroll
        for (int ii = 0; ii < 2; ++ii) {
            int inst = w * 2 + ii;
            int row = inst * 8 + (lane >> 3);            // 0..127
            int cs = (lane & 7) ^ (row & 7);
            ldsdma16(&Ks[inst * 512], &Kp[(k0 + row) * 64 + cs * 8]);
        }
        // --- stage Vs: 16 DMA instrs (4 rows of 256B each), 2 per wave ---
#pragma unroll
        for (int ii = 0; ii < 2; ++ii) {
            int inst = w * 2 + ii;
            int row = inst * 4 + (lane >> 4);            // dh 0..63
            int cs = (lane & 15) ^ (row & 15);
            ldsdma16(&Vs[inst * 512], &Vp[row * 2048 + k0 + cs * 8]);
        }
        float mc[2];
#pragma unroll
        for (int g = 0; g < 2; ++g)
            mc[g] = mask[b * 2048 + k0 + khalf * 64 + g * 32 + l31];
        __syncthreads();                 // DMA drained

        // S = Q.K^T over this wave's 64 keys -> P into wave-private Ps
#pragma unroll
        for (int g = 0; g < 2; ++g) {
            f32x16 z;
#pragma unroll
            for (int r = 0; r < 16; ++r) z[r] = 0.f;
            int rK = khalf * 64 + g * 32 + l31;
#pragma unroll
            for (int s = 0; s < 4; ++s) {
                int chunk = s * 2 + half;
                bf16x8 kf = ld8(&Ks[rK * 64 + ((chunk ^ (rK & 7)) << 3)]);
                z = __builtin_amdgcn_mfma_f32_32x32x16_bf16(qf[s], kf, z, 0, 0, 0);
            }
#pragma unroll
            for (int r = 0; r < 16; ++r) {
                float p = __expf(z[r]) * mc[g];
                int ql = (r & 3) + 8 * (r >> 2) + 4 * half;
                Ps[(w * 32 + ql) * 72 + g * 32 + l31] = f2bf_n(p);
            }
        }
        // wave-private Ps: no barrier

        bf16x8 pf[4];
#pragma unroll
        for (int s = 0; s < 4; ++s)
            pf[s] = ld8(&Ps[(w * 32 + l31) * 72 + s * 16 + half * 8]);

#pragma unroll
        for (int d = 0; d < 2; ++d) {
            int rV = d * 32 + l31;
#pragma unroll
            for (int s = 0; s < 4; ++s) {
                int chunk = khalf * 8 + s * 2 + half;    // key chunk in 128-row
                bf16x8 vf = ld8(&Vs[rV * 128 + ((chunk ^ (rV & 15)) << 3)]);
                accd[d] = __builtin_amdgcn_mfma_f32_32x32x16_bf16(
                    pf[s], vf, accd[d], 0, 0, 0);
            }
        }
#pragma unroll
        for (int s = 0; s < 4; ++s)
            accl = __builtin_amdgcn_mfma_f32_32x32x16_bf16(pf[s], ones_f, accl, 0, 0, 0);
    }

    // ---- split-K merge: khalf=1 writes partials, khalf=0 adds ----
    __syncthreads();
    if (khalf == 1) {
        float* q_ = mrg + qg * 3072;     // [48][64] f32, lane-major rows
#pragma unroll
        for (int r = 0; r < 16; ++r) {
            q_[(r) * 64 + lane]      = accd[0][r];
            q_[(16 + r) * 64 + lane] = accd[1][r];
            q_[(32 + r) * 64 + lane] = accl[r];
        }
    }
    __syncthreads();
    if (khalf == 0) {
        const float* q_ = mrg + qg * 3072;
#pragma unroll
        for (int r = 0; r < 16; ++r) {
            accd[0][r] += q_[(r) * 64 + lane];
            accd[1][r] += q_[(16 + r) * 64 + lane];
            accl[r]    += q_[(32 + r) * 64 + lane];
        }
#pragma unroll
        for (int r = 0; r < 16; ++r) {
            int ql = (r & 3) + 8 * (r >> 2) + 4 * half;
            int q = q0 + qg * 32 + ql;
            float mq = mask[b * 2048 + q];
            float lr = __shfl(accl[r], half * 32, 64);
            float inv = mq / (lr + 1e-13f);
#pragma unroll
            for (int d = 0; d < 2; ++d)
                Xattn[(b * 2048 + q) * 1024 + (bh & 15) * 64 + d * 32 + l31] =
                    f2bf_n(accd[d][r] * inv);
        }
    }
}

// ---------------------------------------------------------------------------
// Output projection — round-8 structure (BK=64 single-buffer), 64x128 tiles,
// grid (64, 8) = 512 blocks. f32 out.
// ---------------------------------------------------------------------------
__global__ __launch_bounds__(256) void oproj_kernel(
    const unsigned short* __restrict__ A, const unsigned short* __restrict__ W,
    const float* __restrict__ bias, float* __restrict__ out)
{
    __shared__ __align__(16) unsigned short As[64 * 64];
    __shared__ __align__(16) unsigned short Bs[128 * 64];

    const int t = threadIdx.x;
    const int lane = t & 63, w = t >> 6;
    const int l15 = lane & 15, grp = lane >> 4;
    const int m0 = blockIdx.x * 64;
    const int e0 = blockIdx.y * 128;
    const int srow = lane >> 3, sc_ = lane & 7;

    f32x4 acc[4][2];
#pragma unroll
    for (int i = 0; i < 4; ++i)
#pragma unroll
        for (int j = 0; j < 2; ++j) acc[i][j] = (f32x4){0.f, 0.f, 0.f, 0.f};

    for (int kt = 0; kt < 16; ++kt) {
        const int k0 = kt * 64;
        __syncthreads();
#pragma unroll
        for (int jj = 0; jj < 2; ++jj) {
            int chunk = w * 2 + jj;
            int row = chunk * 8 + srow;
            int cs = sc_ ^ (row & 7);
            ldsdma16(&As[chunk * 512], &A[(m0 + row) * 1024 + k0 + cs * 8]);
        }
#pragma unroll
        for (int jj = 0; jj < 4; ++jj) {
            int chunk = w * 4 + jj;
            int row = chunk * 8 + srow;
            int cs = sc_ ^ (row & 7);
            ldsdma16(&Bs[chunk * 512], &W[(e0 + row) * 1024 + k0 + cs * 8]);
        }
        __syncthreads();
#pragma unroll
        for (int kk = 0; kk < 64; kk += 32) {
            const int cb = kk >> 3;
            bf16x8 af[4], bfr[2];
#pragma unroll
            for (int i = 0; i < 4; ++i) {
                int r = i * 16 + l15;
                af[i] = ld8(&As[r * 64 + (((cb + grp) ^ (r & 7)) << 3)]);
            }
#pragma unroll
            for (int j = 0; j < 2; ++j) {
                int r = w * 32 + j * 16 + l15;
                bfr[j] = ld8(&Bs[r * 64 + (((cb + grp) ^ (r & 7)) << 3)]);
            }
#pragma unroll
            for (int i = 0; i < 4; ++i)
#pragma unroll
                for (int j = 0; j < 2; ++j)
                    acc[i][j] = __builtin_amdgcn_mfma_f32_16x16x32_bf16(
                        af[i], bfr[j], acc[i][j], 0, 0, 0);
        }
    }

#pragma unroll
    for (int j = 0; j < 2; ++j) {
        int e = e0 + w * 32 + j * 16 + l15;
        float bv_ = bias[e];
#pragma unroll
        for (int i = 0; i < 4; ++i)
#pragma unroll
            for (int r = 0; r < 4; ++r) {
                int token = m0 + i * 16 + grp * 4 + r;
                out[token * 1024 + e] = acc[i][j][r] + bv_;
            }
    }
}

extern "C" void kernel_launch(void* const* d_in, const int* in_sizes, int n_in,
                              void* d_out, int out_size, void* d_ws, size_t ws_size,
                              hipStream_t stream) {
    const float* x    = (const float*)d_in[0];
    const float* mask = (const float*)d_in[1];
    const float* Wq   = (const float*)d_in[2];
    const float* bq   = (const float*)d_in[3];
    const float* Wk   = (const float*)d_in[4];
    const float* bk   = (const float*)d_in[5];
    const float* Wv   = (const float*)d_in[6];
    const float* bv   = (const float*)d_in[7];
    const float* Wo   = (const float*)d_in[8];
    const float* bo   = (const float*)d_in[9];
    float* out = (float*)d_out;

    unsigned short* Qws   = (unsigned short*)d_ws;   // u16 element offsets:
    unsigned short* Kws   = Qws + 4194304;
    unsigned short* VT    = Qws + 8388608;
    unsigned short* Xattn = Qws + 12582912;
    unsigned short* Xb    = Qws + 16777216;
    unsigned short* Wb    = Qws + 20971520;          // [Wq|Wk|Wv|Wo], end = 48 MB

    conv_kernel<<<dim3(8192), 256, 0, stream>>>(x, Wq, Wk, Wv, Wo, Xb, Wb);
    qkv_kernel<<<dim3(32, 24), 256, 0, stream>>>(Xb, Wb, bq, bk, bv, Qws, Kws, VT);
    attn_kernel<<<dim3(16, 32), 512, 0, stream>>>(Qws, Kws, VT, mask, Xattn);
    oproj_kernel<<<dim3(64, 8), 256, 0, stream>>>(Xattn, Wb + 3145728, bo, out);
}